// Round 1
// baseline (473.760 us; speedup 1.0000x reference)
//
#include <hip/hip_runtime.h>
#include <math.h>

#define BN  4
#define LL  4096
#define CC  96
#define DIN 192
#define KD  4
#define NS  16
#define RK  6
#define QLEN 64
#define JCH  64   // LL/QLEN

__device__ __forceinline__ float sigmoidf_(float x){ return 1.f/(1.f+__expf(-x)); }
__device__ __forceinline__ float softplusf_(float x){ return x > 20.f ? x : log1pf(__expf(x)); }

// ---------------- GEMM building blocks ----------------
// LDS A: [64 rows][96 +2 pad], LDS B: [96 k][64 cols]

__device__ __forceinline__ void stageB_(const float* __restrict__ WT, int NTOT, int KTOT, int k0, int c0,
                                        float* __restrict__ lB, int tid){
  for (int idx = tid; idx < 96*64; idx += 256){
    int k = idx >> 6, c = idx & 63;
    int gk = k0 + k, gc = c0 + c;
    lB[idx] = (gc < NTOT && gk < KTOT) ? WT[(size_t)gk*NTOT + gc] : 0.f;
  }
}

__device__ __forceinline__ void stageA_raw_(const float* __restrict__ A, int SR, int row0, int k0,
                                            float* __restrict__ lA, int tid){
  for (int idx = tid; idx < 64*96; idx += 256){
    int r = idx / 96, k = idx - r*96;
    lA[r*98 + k] = A[(size_t)(row0 + r)*SR + k0 + k];
  }
}

__device__ __forceinline__ void stageA_ln_(const float* __restrict__ A, int row0,
                                           const float* __restrict__ w, const float* __restrict__ bv,
                                           float* __restrict__ lA, float* __restrict__ lmu,
                                           float* __restrict__ liv, int tid){
  for (int idx = tid; idx < 64*96; idx += 256){
    int r = idx / 96, k = idx - r*96;
    lA[r*98 + k] = A[(size_t)(row0 + r)*96 + k];
  }
  __syncthreads();
  {
    int r = tid >> 2, p = tid & 3;
    float s = 0.f, ss = 0.f;
    #pragma unroll
    for (int i = 0; i < 24; i++){ float v = lA[r*98 + p*24 + i]; s += v; ss += v*v; }
    s  += __shfl_xor(s, 1);  ss += __shfl_xor(ss, 1);
    s  += __shfl_xor(s, 2);  ss += __shfl_xor(ss, 2);
    if (p == 0){
      float mu = s*(1.f/96.f);
      float var = ss*(1.f/96.f) - mu*mu;
      lmu[r] = mu; liv[r] = rsqrtf(var + 1e-5f);
    }
  }
  __syncthreads();
  for (int idx = tid; idx < 64*96; idx += 256){
    int r = idx / 96, k = idx - r*96;
    float v = lA[r*98 + k];
    lA[r*98 + k] = (v - lmu[r])*liv[r]*w[k] + bv[k];
  }
}

__device__ __forceinline__ void core96_(const float* __restrict__ lA, const float* __restrict__ lB,
                                        int r0, int c0, float acc[4][4]){
  #pragma unroll 4
  for (int k = 0; k < 96; k += 2){
    float2 a[4];
    #pragma unroll
    for (int i = 0; i < 4; i++) a[i] = *(const float2*)&lA[(r0+i)*98 + k];
    float4 b0 = *(const float4*)&lB[k*64 + c0];
    float4 b1 = *(const float4*)&lB[(k+1)*64 + c0];
    #pragma unroll
    for (int i = 0; i < 4; i++){
      acc[i][0] = fmaf(a[i].x, b0.x, acc[i][0]); acc[i][0] = fmaf(a[i].y, b1.x, acc[i][0]);
      acc[i][1] = fmaf(a[i].x, b0.y, acc[i][1]); acc[i][1] = fmaf(a[i].y, b1.y, acc[i][1]);
      acc[i][2] = fmaf(a[i].x, b0.z, acc[i][2]); acc[i][2] = fmaf(a[i].y, b1.z, acc[i][2]);
      acc[i][3] = fmaf(a[i].x, b0.w, acc[i][3]); acc[i][3] = fmaf(a[i].y, b1.w, acc[i][3]);
    }
  }
}

// ---------------- K0: weight transposes ----------------
__global__ __launch_bounds__(256) void k0_tr(const float* __restrict__ ipw, const float* __restrict__ xpw,
    const float* __restrict__ opw, const float* __restrict__ f1w, const float* __restrict__ f3w,
    float* __restrict__ WT1, float* __restrict__ WT3, float* __restrict__ WT8,
    float* __restrict__ WT9, float* __restrict__ WT11){
  int tid = blockIdx.x*256 + threadIdx.x;
  if (tid < 96*384){ int k = tid/384, j = tid%384; WT1[tid]  = ipw[j*96 + k]; }
  if (tid < 192*152){ int d = tid/152, kc = tid%152; WT3[tid] = xpw[kc*192 + d]; }
  if (tid < 192*96){ int d = tid/96, c = tid%96; WT8[tid]  = opw[c*192 + d]; }
  if (tid < 96*192){ int k = tid/192, j = tid%192; WT9[tid]  = f1w[j*96 + k]; }
  if (tid < 96*96){  int k = tid/96,  j = tid%96;  WT11[tid] = f3w[j*96 + k]; }
}

// ---------------- K1: LN1 + in_proj ----------------
__global__ __launch_bounds__(256) void k1_ln_inproj(const float* __restrict__ x,
    const float* __restrict__ lnw, const float* __restrict__ lnb,
    const float* __restrict__ WT, float* __restrict__ xconv, float* __restrict__ z){
  __shared__ float lA[64*98], lB[96*64], lmu[64], liv[64];
  int tid = threadIdx.x;
  int row0 = blockIdx.x * 64, c0 = blockIdx.y * 64;
  stageA_ln_(x, row0, lnw, lnb, lA, lmu, liv, tid);
  stageB_(WT, 384, 96, 0, c0, lB, tid);
  __syncthreads();
  float acc[4][4] = {};
  int ty = tid >> 4, tx = tid & 15;
  core96_(lA, lB, ty*4, tx*4, acc);
  #pragma unroll
  for (int i = 0; i < 4; i++){
    int r = row0 + ty*4 + i;
    #pragma unroll
    for (int jj = 0; jj < 4; jj++){
      int c = c0 + tx*4 + jj;
      if (c < 192) xconv[(size_t)r*192 + c] = acc[i][jj];
      else         z[(size_t)r*192 + (c - 192)] = acc[i][jj];
    }
  }
}

// ---------------- K2: depthwise 3x3 conv + SiLU ----------------
__global__ __launch_bounds__(256) void k2_conv(const float* __restrict__ xc,
    const float* __restrict__ cw, const float* __restrict__ cb, float* __restrict__ xx){
  int tid = blockIdx.x*256 + threadIdx.x;
  if (tid >= BN*LL*DIN) return;
  int d = tid % DIN; int bl = tid / DIN;
  int l = bl & 4095; int b = bl >> 12;
  int h = l >> 6, w = l & 63;
  float s = cb[d];
  #pragma unroll
  for (int dh = -1; dh <= 1; dh++){
    int h2 = h + dh; if (h2 < 0 || h2 > 63) continue;
    #pragma unroll
    for (int dw = -1; dw <= 1; dw++){
      int w2 = w + dw; if (w2 < 0 || w2 > 63) continue;
      s = fmaf(xc[((size_t)((b<<12) | (h2<<6) | w2))*DIN + d], cw[d*9 + (dh+1)*3 + (dw+1)], s);
    }
  }
  xx[tid] = s * sigmoidf_(s);
}

// ---------------- K3: x_proj for 4 directions (scatter) ----------------
__global__ __launch_bounds__(256) void k3_xdbl(const float* __restrict__ xx,
    const float* __restrict__ WT, float* __restrict__ xdbl){
  __shared__ float lA[64*98], lB[96*64];
  int tid = threadIdx.x;
  int row0 = blockIdx.x * 64, c0 = blockIdx.y * 64;
  float acc[4][4] = {};
  int ty = tid >> 4, tx = tid & 15;
  for (int k0 = 0; k0 < 192; k0 += 96){
    __syncthreads();
    stageA_raw_(xx, 192, row0, k0, lA, tid);
    stageB_(WT, 152, 192, k0, c0, lB, tid);
    __syncthreads();
    core96_(lA, lB, ty*4, tx*4, acc);
  }
  #pragma unroll
  for (int i = 0; i < 4; i++){
    int r = row0 + ty*4 + i;
    int b = r >> 12, l = r & 4095;
    int hh = l >> 6, ww = l & 63;
    int lt = (ww << 6) | hh;
    #pragma unroll
    for (int jj = 0; jj < 4; jj++){
      int kc = c0 + tx*4 + jj;
      if (kc < 152){
        int k = kc / 38, cc = kc - k*38;
        int pos = (k == 0) ? l : (k == 1) ? lt : (k == 2) ? (4095 - l) : (4095 - lt);
        xdbl[(((size_t)(b*4 + k))*4096 + pos)*38 + cc] = acc[i][jj];
      }
    }
  }
}

// ---------------- scan helpers ----------------
__device__ __forceinline__ int src_of(int k, int t){
  if (k == 0) return t;
  if (k == 1) return ((t & 63) << 6) | (t >> 6);
  if (k == 2) return 4095 - t;
  int tt = 4095 - t; return ((tt & 63) << 6) | (tt >> 6);
}

// ---------------- K4: scan pass 1 (chunk summaries) ----------------
__global__ __launch_bounds__(192) void k4_scan1(const float* __restrict__ xdbl, const float* __restrict__ xx,
    const float* __restrict__ dtw, const float* __restrict__ dtb, const float* __restrict__ alogs,
    float* __restrict__ summ){
  int bkj = blockIdx.x;
  int j = bkj & 63, k = (bkj >> 6) & 3, b = bkj >> 8;
  int d = threadIdx.x;
  float wv[6];
  #pragma unroll
  for (int r = 0; r < 6; r++) wv[r] = dtw[(k*DIN + d)*6 + r];
  float bb = dtb[k*DIN + d];
  float A2[16];
  #pragma unroll
  for (int n = 0; n < 16; n++) A2[n] = -__expf(alogs[(k*DIN + d)*16 + n]) * 1.44269504088896f;
  float h[16], ap[16];
  #pragma unroll
  for (int n = 0; n < 16; n++){ h[n] = 0.f; ap[n] = 1.f; }
  const float* rec = xdbl + (((size_t)(b*4 + k))*4096 + j*QLEN)*38;
  const float* xb = xx + (size_t)b*4096*DIN;
  for (int t0 = 0; t0 < QLEN; t0++){
    int t = j*QLEN + t0;
    float draw = bb;
    #pragma unroll
    for (int r = 0; r < 6; r++) draw = fmaf(wv[r], rec[r], draw);
    float delta = softplusf_(draw);
    float u = xb[(size_t)src_of(k, t)*DIN + d];
    float du = delta * u;
    #pragma unroll
    for (int n = 0; n < 16; n++){
      float a = exp2f(A2[n] * delta);
      h[n] = fmaf(a, h[n], du * rec[6 + n]);
      ap[n] *= a;
    }
    rec += 38;
  }
  float* out = summ + (size_t)bkj * 32 * DIN;
  #pragma unroll
  for (int n = 0; n < 16; n++){
    out[n*DIN + d] = ap[n];
    out[(16 + n)*DIN + d] = h[n];
  }
}

// ---------------- K5: combine chunk summaries ----------------
__global__ __launch_bounds__(192) void k5_comb(const float* __restrict__ summ, float* __restrict__ hinit){
  int bkn = blockIdx.x;          // (b*4+k)*16 + n
  int n = bkn & 15, bk = bkn >> 4;
  int d = threadIdx.x;
  float hc = 0.f;
  for (int j = 0; j < JCH; j++){
    size_t sb = ((size_t)(bk*JCH + j))*32*DIN;
    hinit[((size_t)(bk*JCH + j))*16*DIN + n*DIN + d] = hc;
    float a  = summ[sb + n*DIN + d];
    float he = summ[sb + (16+n)*DIN + d];
    hc = fmaf(a, hc, he);
  }
}

// ---------------- K6: scan pass 2 (emit ys) ----------------
__global__ __launch_bounds__(192) void k6_scan2(const float* __restrict__ xdbl, const float* __restrict__ xx,
    const float* __restrict__ dtw, const float* __restrict__ dtb, const float* __restrict__ alogs,
    const float* __restrict__ Ds, const float* __restrict__ hinit, float* __restrict__ ys){
  int bkj = blockIdx.x;
  int j = bkj & 63, k = (bkj >> 6) & 3, b = bkj >> 8;
  int d = threadIdx.x;
  float wv[6];
  #pragma unroll
  for (int r = 0; r < 6; r++) wv[r] = dtw[(k*DIN + d)*6 + r];
  float bb = dtb[k*DIN + d];
  float A2[16];
  #pragma unroll
  for (int n = 0; n < 16; n++) A2[n] = -__expf(alogs[(k*DIN + d)*16 + n]) * 1.44269504088896f;
  float Dv = Ds[k*DIN + d];
  float h[16];
  const float* hi = hinit + (size_t)bkj*16*DIN;
  #pragma unroll
  for (int n = 0; n < 16; n++) h[n] = hi[n*DIN + d];
  const float* rec = xdbl + (((size_t)(b*4 + k))*4096 + j*QLEN)*38;
  const float* xb = xx + (size_t)b*4096*DIN;
  float* yb = ys + (((size_t)(b*4 + k))*4096 + j*QLEN)*DIN + d;
  for (int t0 = 0; t0 < QLEN; t0++){
    int t = j*QLEN + t0;
    float draw = bb;
    #pragma unroll
    for (int r = 0; r < 6; r++) draw = fmaf(wv[r], rec[r], draw);
    float delta = softplusf_(draw);
    float u = xb[(size_t)src_of(k, t)*DIN + d];
    float du = delta * u;
    float y = 0.f;
    #pragma unroll
    for (int n = 0; n < 16; n++){
      float a = exp2f(A2[n] * delta);
      h[n] = fmaf(a, h[n], du * rec[6 + n]);
      y = fmaf(h[n], rec[22 + n], y);
    }
    y = fmaf(Dv, u, y);
    yb[(size_t)t0*DIN] = y;
    rec += 38;
  }
}

// ---------------- K7: merge directions + out_norm + gate ----------------
__global__ __launch_bounds__(192) void k7_comb(const float* __restrict__ ys, const float* __restrict__ z,
    const float* __restrict__ onw, const float* __restrict__ onb, float* __restrict__ gated){
  int row = blockIdx.x;          // b*4096 + l
  int b = row >> 12, l = row & 4095;
  int d = threadIdx.x;
  int hh = l >> 6, ww = l & 63;
  int lt = (ww << 6) | hh;
  size_t base = (size_t)b * 4 * 4096 * DIN;
  float y = ys[base + ((size_t)0*4096 + l)*DIN + d]
          + ys[base + ((size_t)1*4096 + lt)*DIN + d]
          + ys[base + ((size_t)2*4096 + (4095 - l))*DIN + d]
          + ys[base + ((size_t)3*4096 + (4095 - lt))*DIN + d];
  __shared__ float red[6];
  float s = y, ss = y*y;
  #pragma unroll
  for (int off = 32; off > 0; off >>= 1){ s += __shfl_down(s, off); ss += __shfl_down(ss, off); }
  int wid = d >> 6;
  if ((d & 63) == 0){ red[wid] = s; red[3 + wid] = ss; }
  __syncthreads();
  float S = red[0] + red[1] + red[2], SS = red[3] + red[4] + red[5];
  float mu = S * (1.f/192.f);
  float var = SS * (1.f/192.f) - mu*mu;
  float iv = rsqrtf(var + 1e-5f);
  float yn = (y - mu)*iv*onw[d] + onb[d];
  float zv = z[(size_t)row*DIN + d];
  gated[(size_t)row*DIN + d] = yn * zv * sigmoidf_(zv);
}

// ---------------- K8: out_proj + skip1 residual ----------------
__global__ __launch_bounds__(256) void k8_outproj(const float* __restrict__ gated, const float* __restrict__ WT,
    const float* __restrict__ inp, const float* __restrict__ skip1, float* __restrict__ x1){
  __shared__ float lA[64*98], lB[96*64];
  int tid = threadIdx.x;
  int row0 = blockIdx.x*64, c0 = blockIdx.y*64;
  float acc[4][4] = {};
  int ty = tid >> 4, tx = tid & 15;
  for (int k0 = 0; k0 < 192; k0 += 96){
    __syncthreads();
    stageA_raw_(gated, 192, row0, k0, lA, tid);
    stageB_(WT, 96, 192, k0, c0, lB, tid);
    __syncthreads();
    core96_(lA, lB, ty*4, tx*4, acc);
  }
  #pragma unroll
  for (int i = 0; i < 4; i++){
    int r = row0 + ty*4 + i;
    #pragma unroll
    for (int jj = 0; jj < 4; jj++){
      int c = c0 + tx*4 + jj;
      if (c < 96) x1[(size_t)r*96 + c] = inp[(size_t)r*96 + c]*skip1[c] + acc[i][jj];
    }
  }
}

// ---------------- K9: LN2 + ffn1 (1x1) + bias ----------------
__global__ __launch_bounds__(256) void k9_ffn1(const float* __restrict__ x1,
    const float* __restrict__ lnw, const float* __restrict__ lnb,
    const float* __restrict__ WT, const float* __restrict__ b1, float* __restrict__ t1){
  __shared__ float lA[64*98], lB[96*64], lmu[64], liv[64];
  int tid = threadIdx.x;
  int row0 = blockIdx.x * 64, c0 = blockIdx.y * 64;
  stageA_ln_(x1, row0, lnw, lnb, lA, lmu, liv, tid);
  stageB_(WT, 192, 96, 0, c0, lB, tid);
  __syncthreads();
  float acc[4][4] = {};
  int ty = tid >> 4, tx = tid & 15;
  core96_(lA, lB, ty*4, tx*4, acc);
  #pragma unroll
  for (int i = 0; i < 4; i++){
    int r = row0 + ty*4 + i;
    #pragma unroll
    for (int jj = 0; jj < 4; jj++){
      int c = c0 + tx*4 + jj;
      t1[(size_t)r*192 + c] = acc[i][jj] + b1[c];
    }
  }
}

// ---------------- K10: depthwise 3x3 + GLU (exact gelu) ----------------
__global__ __launch_bounds__(256) void k10_dwglu(const float* __restrict__ t1, const float* __restrict__ cw2,
    const float* __restrict__ cb2, float* __restrict__ g){
  int tid = blockIdx.x*256 + threadIdx.x;
  if (tid >= BN*LL*CC) return;
  int c = tid % 96; int bl = tid / 96;
  int l = bl & 4095, b = bl >> 12;
  int h = l >> 6, w = l & 63;
  float s1 = cb2[c], s2 = cb2[c + 96];
  #pragma unroll
  for (int dh = -1; dh <= 1; dh++){
    int h2 = h + dh; if (h2 < 0 || h2 > 63) continue;
    #pragma unroll
    for (int dw = -1; dw <= 1; dw++){
      int w2 = w + dw; if (w2 < 0 || w2 > 63) continue;
      const float* p = &t1[((size_t)((b<<12) | (h2<<6) | w2))*DIN];
      int tap = (dh+1)*3 + (dw+1);
      s1 = fmaf(p[c],      cw2[c*9 + tap],        s1);
      s2 = fmaf(p[c + 96], cw2[(c + 96)*9 + tap], s2);
    }
  }
  float ge = 0.5f * s1 * (1.f + erff(s1 * 0.7071067811865475f));
  g[tid] = ge * s2;
}

// ---------------- K11: ffn3 (1x1) + skip2 residual ----------------
__global__ __launch_bounds__(256) void k11_ffn3(const float* __restrict__ g, const float* __restrict__ WT,
    const float* __restrict__ x1, const float* __restrict__ skip2, const float* __restrict__ b3,
    float* __restrict__ out){
  __shared__ float lA[64*98], lB[96*64];
  int tid = threadIdx.x;
  int row0 = blockIdx.x*64, c0 = blockIdx.y*64;
  stageA_raw_(g, 96, row0, 0, lA, tid);
  stageB_(WT, 96, 96, 0, c0, lB, tid);
  __syncthreads();
  float acc[4][4] = {};
  int ty = tid >> 4, tx = tid & 15;
  core96_(lA, lB, ty*4, tx*4, acc);
  #pragma unroll
  for (int i = 0; i < 4; i++){
    int r = row0 + ty*4 + i;
    #pragma unroll
    for (int jj = 0; jj < 4; jj++){
      int c = c0 + tx*4 + jj;
      if (c < 96) out[(size_t)r*96 + c] = x1[(size_t)r*96 + c]*skip2[c] + acc[i][jj] + b3[c];
    }
  }
}

// ---------------- launch ----------------
extern "C" void kernel_launch(void* const* d_in, const int* in_sizes, int n_in,
                              void* d_out, int out_size, void* d_ws, size_t ws_size,
                              hipStream_t stream){
  const float* input = (const float*)d_in[0];
  const float* ln1w  = (const float*)d_in[3];
  const float* ln1b  = (const float*)d_in[4];
  const float* skip1 = (const float*)d_in[5];
  const float* skip2 = (const float*)d_in[6];
  const float* ln2w  = (const float*)d_in[7];
  const float* ln2b  = (const float*)d_in[8];
  const float* ipw   = (const float*)d_in[9];
  const float* convw = (const float*)d_in[10];
  const float* convb = (const float*)d_in[11];
  const float* xpw   = (const float*)d_in[12];
  const float* dtw   = (const float*)d_in[13];
  const float* dtb   = (const float*)d_in[14];
  const float* alogs = (const float*)d_in[15];
  const float* Ds    = (const float*)d_in[16];
  const float* onw   = (const float*)d_in[17];
  const float* onb   = (const float*)d_in[18];
  const float* opw   = (const float*)d_in[19];
  const float* f1w   = (const float*)d_in[20];
  const float* f1b   = (const float*)d_in[21];
  const float* f2w   = (const float*)d_in[22];
  const float* f2b   = (const float*)d_in[23];
  const float* f3w   = (const float*)d_in[24];
  const float* f3b   = (const float*)d_in[25];
  float* out = (float*)d_out;
  float* ws  = (float*)d_ws;

  // ws offsets (in floats)
  const size_t O_WT1   = 0;            // 36864
  const size_t O_WT3   = 36864;        // 29184
  const size_t O_WT8   = 66048;        // 18432
  const size_t O_WT9   = 84480;        // 18432
  const size_t O_WT11  = 102912;       // 9216
  const size_t O_XCONV = 112640;       // 3145728
  const size_t O_Z     = 3258368;      // 3145728
  const size_t O_XX    = 6404096;      // 3145728
  const size_t O_XDBL  = 9549824;      // 2490368
  const size_t O_SUMM  = 12040192;     // 6291456
  const size_t O_HINIT = 18331648;     // 3145728
  const size_t O_YS    = 21477376;     // 12582912  (end 34060288 floats = 136.2 MB)
  const size_t O_GATED = O_XCONV;      // reuse (xconv dead after k2)
  const size_t O_X1    = O_XX;         // reuse (xx dead after k6)
  const size_t O_T1    = O_Z;          // reuse (z dead after k7)
  const size_t O_G     = O_XDBL;       // reuse (xdbl dead after k6)

  float* WT1  = ws + O_WT1;  float* WT3  = ws + O_WT3;  float* WT8 = ws + O_WT8;
  float* WT9  = ws + O_WT9;  float* WT11 = ws + O_WT11;
  float* xconv = ws + O_XCONV; float* z = ws + O_Z; float* xx = ws + O_XX;
  float* xdbl = ws + O_XDBL; float* summ = ws + O_SUMM; float* hinit = ws + O_HINIT;
  float* ys = ws + O_YS; float* gated = ws + O_GATED; float* x1 = ws + O_X1;
  float* t1 = ws + O_T1; float* g = ws + O_G;

  k0_tr<<<144, 256, 0, stream>>>(ipw, xpw, opw, f1w, f3w, WT1, WT3, WT8, WT9, WT11);
  k1_ln_inproj<<<dim3(256, 6), 256, 0, stream>>>(input, ln1w, ln1b, WT1, xconv, z);
  k2_conv<<<(BN*LL*DIN + 255)/256, 256, 0, stream>>>(xconv, convw, convb, xx);
  k3_xdbl<<<dim3(256, 3), 256, 0, stream>>>(xx, WT3, xdbl);
  k4_scan1<<<BN*KD*JCH, 192, 0, stream>>>(xdbl, xx, dtw, dtb, alogs, summ);
  k5_comb<<<BN*KD*NS, 192, 0, stream>>>(summ, hinit);
  k6_scan2<<<BN*KD*JCH, 192, 0, stream>>>(xdbl, xx, dtw, dtb, alogs, Ds, hinit, ys);
  k7_comb<<<BN*LL, 192, 0, stream>>>(ys, z, onw, onb, gated);
  k8_outproj<<<dim3(256, 2), 256, 0, stream>>>(gated, WT8, input, skip1, x1);
  k9_ffn1<<<dim3(256, 3), 256, 0, stream>>>(x1, ln2w, ln2b, WT9, f1b, t1);
  k10_dwglu<<<(BN*LL*CC + 255)/256, 256, 0, stream>>>(t1, f2w, f2b, g);
  k11_ffn3<<<dim3(256, 2), 256, 0, stream>>>(g, WT11, x1, skip2, f3b, out);
  (void)in_sizes; (void)n_in; (void)out_size; (void)ws_size;
}

// Round 2
// 450.514 us; speedup vs baseline: 1.0516x; 1.0516x over previous
//
#include <hip/hip_runtime.h>
#include <math.h>

#define BN  4
#define LL  4096
#define CC  96
#define DIN 192
#define KD  4
#define NS  16
#define RK  6
#define QLEN 32
#define JCH  128   // LL/QLEN
#define REC  40    // padded record stride (floats), 160B aligned

__device__ __forceinline__ float sigmoidf_(float x){ return 1.f/(1.f+__expf(-x)); }
__device__ __forceinline__ float softplusf_(float x){ return x > 20.f ? x : log1pf(__expf(x)); }

// ---------------- GEMM building blocks ----------------
// LDS A: [64 rows][96 +2 pad], LDS B: [96 k][64 cols]

__device__ __forceinline__ void stageB_(const float* __restrict__ WT, int NTOT, int KTOT, int k0, int c0,
                                        float* __restrict__ lB, int tid){
  for (int idx = tid; idx < 96*64; idx += 256){
    int k = idx >> 6, c = idx & 63;
    int gk = k0 + k, gc = c0 + c;
    lB[idx] = (gc < NTOT && gk < KTOT) ? WT[(size_t)gk*NTOT + gc] : 0.f;
  }
}

__device__ __forceinline__ void stageA_raw_(const float* __restrict__ A, int SR, int row0, int k0,
                                            float* __restrict__ lA, int tid){
  for (int idx = tid; idx < 64*96; idx += 256){
    int r = idx / 96, k = idx - r*96;
    lA[r*98 + k] = A[(size_t)(row0 + r)*SR + k0 + k];
  }
}

__device__ __forceinline__ void stageA_ln_(const float* __restrict__ A, int row0,
                                           const float* __restrict__ w, const float* __restrict__ bv,
                                           float* __restrict__ lA, float* __restrict__ lmu,
                                           float* __restrict__ liv, int tid){
  for (int idx = tid; idx < 64*96; idx += 256){
    int r = idx / 96, k = idx - r*96;
    lA[r*98 + k] = A[(size_t)(row0 + r)*96 + k];
  }
  __syncthreads();
  {
    int r = tid >> 2, p = tid & 3;
    float s = 0.f, ss = 0.f;
    #pragma unroll
    for (int i = 0; i < 24; i++){ float v = lA[r*98 + p*24 + i]; s += v; ss += v*v; }
    s  += __shfl_xor(s, 1);  ss += __shfl_xor(ss, 1);
    s  += __shfl_xor(s, 2);  ss += __shfl_xor(ss, 2);
    if (p == 0){
      float mu = s*(1.f/96.f);
      float var = ss*(1.f/96.f) - mu*mu;
      lmu[r] = mu; liv[r] = rsqrtf(var + 1e-5f);
    }
  }
  __syncthreads();
  for (int idx = tid; idx < 64*96; idx += 256){
    int r = idx / 96, k = idx - r*96;
    float v = lA[r*98 + k];
    lA[r*98 + k] = (v - lmu[r])*liv[r]*w[k] + bv[k];
  }
}

__device__ __forceinline__ void core96_(const float* __restrict__ lA, const float* __restrict__ lB,
                                        int r0, int c0, float acc[4][4]){
  #pragma unroll 4
  for (int k = 0; k < 96; k += 2){
    float2 a[4];
    #pragma unroll
    for (int i = 0; i < 4; i++) a[i] = *(const float2*)&lA[(r0+i)*98 + k];
    float4 b0 = *(const float4*)&lB[k*64 + c0];
    float4 b1 = *(const float4*)&lB[(k+1)*64 + c0];
    #pragma unroll
    for (int i = 0; i < 4; i++){
      acc[i][0] = fmaf(a[i].x, b0.x, acc[i][0]); acc[i][0] = fmaf(a[i].y, b1.x, acc[i][0]);
      acc[i][1] = fmaf(a[i].x, b0.y, acc[i][1]); acc[i][1] = fmaf(a[i].y, b1.y, acc[i][1]);
      acc[i][2] = fmaf(a[i].x, b0.z, acc[i][2]); acc[i][2] = fmaf(a[i].y, b1.z, acc[i][2]);
      acc[i][3] = fmaf(a[i].x, b0.w, acc[i][3]); acc[i][3] = fmaf(a[i].y, b1.w, acc[i][3]);
    }
  }
}

// ---------------- K0: weight transposes ----------------
__global__ __launch_bounds__(256) void k0_tr(const float* __restrict__ ipw, const float* __restrict__ xpw,
    const float* __restrict__ opw, const float* __restrict__ f1w, const float* __restrict__ f3w,
    float* __restrict__ WT1, float* __restrict__ WT3, float* __restrict__ WT8,
    float* __restrict__ WT9, float* __restrict__ WT11){
  int tid = blockIdx.x*256 + threadIdx.x;
  if (tid < 96*384){ int k = tid/384, j = tid%384; WT1[tid]  = ipw[j*96 + k]; }
  if (tid < 192*152){ int d = tid/152, kc = tid%152; WT3[tid] = xpw[kc*192 + d]; }
  if (tid < 192*96){ int d = tid/96, c = tid%96; WT8[tid]  = opw[c*192 + d]; }
  if (tid < 96*192){ int k = tid/192, j = tid%192; WT9[tid]  = f1w[j*96 + k]; }
  if (tid < 96*96){  int k = tid/96,  j = tid%96;  WT11[tid] = f3w[j*96 + k]; }
}

// ---------------- K1: LN1 + in_proj ----------------
__global__ __launch_bounds__(256) void k1_ln_inproj(const float* __restrict__ x,
    const float* __restrict__ lnw, const float* __restrict__ lnb,
    const float* __restrict__ WT, float* __restrict__ xconv, float* __restrict__ z){
  __shared__ float lA[64*98], lB[96*64], lmu[64], liv[64];
  int tid = threadIdx.x;
  int row0 = blockIdx.x * 64, c0 = blockIdx.y * 64;
  stageA_ln_(x, row0, lnw, lnb, lA, lmu, liv, tid);
  stageB_(WT, 384, 96, 0, c0, lB, tid);
  __syncthreads();
  float acc[4][4] = {};
  int ty = tid >> 4, tx = tid & 15;
  core96_(lA, lB, ty*4, tx*4, acc);
  #pragma unroll
  for (int i = 0; i < 4; i++){
    int r = row0 + ty*4 + i;
    #pragma unroll
    for (int jj = 0; jj < 4; jj++){
      int c = c0 + tx*4 + jj;
      if (c < 192) xconv[(size_t)r*192 + c] = acc[i][jj];
      else         z[(size_t)r*192 + (c - 192)] = acc[i][jj];
    }
  }
}

// ---------------- K2: depthwise 3x3 conv + SiLU ----------------
__global__ __launch_bounds__(256) void k2_conv(const float* __restrict__ xc,
    const float* __restrict__ cw, const float* __restrict__ cb, float* __restrict__ xx){
  int tid = blockIdx.x*256 + threadIdx.x;
  if (tid >= BN*LL*DIN) return;
  int d = tid % DIN; int bl = tid / DIN;
  int l = bl & 4095; int b = bl >> 12;
  int h = l >> 6, w = l & 63;
  float s = cb[d];
  #pragma unroll
  for (int dh = -1; dh <= 1; dh++){
    int h2 = h + dh; if (h2 < 0 || h2 > 63) continue;
    #pragma unroll
    for (int dw = -1; dw <= 1; dw++){
      int w2 = w + dw; if (w2 < 0 || w2 > 63) continue;
      s = fmaf(xc[((size_t)((b<<12) | (h2<<6) | w2))*DIN + d], cw[d*9 + (dh+1)*3 + (dw+1)], s);
    }
  }
  xx[tid] = s * sigmoidf_(s);
}

// ---------------- K3: x_proj for 4 directions (scatter, padded records) ----------------
__global__ __launch_bounds__(256) void k3_xdbl(const float* __restrict__ xx,
    const float* __restrict__ WT, float* __restrict__ xdbl){
  __shared__ float lA[64*98], lB[96*64];
  int tid = threadIdx.x;
  int row0 = blockIdx.x * 64, c0 = blockIdx.y * 64;
  float acc[4][4] = {};
  int ty = tid >> 4, tx = tid & 15;
  for (int k0 = 0; k0 < 192; k0 += 96){
    __syncthreads();
    stageA_raw_(xx, 192, row0, k0, lA, tid);
    stageB_(WT, 152, 192, k0, c0, lB, tid);
    __syncthreads();
    core96_(lA, lB, ty*4, tx*4, acc);
  }
  #pragma unroll
  for (int i = 0; i < 4; i++){
    int r = row0 + ty*4 + i;
    int b = r >> 12, l = r & 4095;
    int hh = l >> 6, ww = l & 63;
    int lt = (ww << 6) | hh;
    #pragma unroll
    for (int jj = 0; jj < 4; jj++){
      int kc = c0 + tx*4 + jj;
      if (kc < 152){
        int k = kc / 38, cc = kc - k*38;
        int pos = (k == 0) ? l : (k == 1) ? lt : (k == 2) ? (4095 - l) : (4095 - lt);
        xdbl[(((size_t)(b*4 + k))*4096 + pos)*REC + cc] = acc[i][jj];
      }
    }
  }
}

// ---------------- scan helpers ----------------
__device__ __forceinline__ int src_of(int k, int t){
  if (k == 0) return t;
  if (k == 1) return ((t & 63) << 6) | (t >> 6);
  if (k == 2) return 4095 - t;
  int tt = 4095 - t; return ((tt & 63) << 6) | (tt >> 6);
}

// ---------------- K4: scan pass 1 (chunk summaries) ----------------
__global__ __launch_bounds__(192) void k4_scan1(const float* __restrict__ xdbl, const float* __restrict__ xx,
    const float* __restrict__ dtw, const float* __restrict__ dtb, const float* __restrict__ alogs,
    float* __restrict__ summ){
  int bkj = blockIdx.x;
  int j = bkj & (JCH-1), k = (bkj >> 7) & 3, b = bkj >> 9;
  int d = threadIdx.x;
  float wv[6];
  #pragma unroll
  for (int r = 0; r < 6; r++) wv[r] = dtw[(k*DIN + d)*6 + r];
  float bb = dtb[k*DIN + d];
  float A2[16];
  #pragma unroll
  for (int n = 0; n < 16; n++) A2[n] = -__expf(alogs[(k*DIN + d)*16 + n]) * 1.44269504088896f;
  float h[16], ap[16];
  #pragma unroll
  for (int n = 0; n < 16; n++){ h[n] = 0.f; ap[n] = 1.f; }
  const float4* r4 = (const float4*)(xdbl + (((size_t)(b*4 + k))*4096 + j*QLEN)*REC);
  const float* xb = xx + (size_t)b*4096*DIN;
  for (int t0 = 0; t0 < QLEN; t0++){
    int t = j*QLEN + t0;
    float4 q[6];
    #pragma unroll
    for (int i = 0; i < 6; i++) q[i] = r4[i];
    const float* rr = (const float*)q;
    float u = xb[(size_t)src_of(k, t)*DIN + d];
    float draw = bb;
    #pragma unroll
    for (int r = 0; r < 6; r++) draw = fmaf(wv[r], rr[r], draw);
    float delta = softplusf_(draw);
    float du = delta * u;
    #pragma unroll
    for (int n = 0; n < 16; n++){
      float a = exp2f(A2[n] * delta);
      h[n] = fmaf(a, h[n], du * rr[6 + n]);
      ap[n] *= a;
    }
    r4 += REC/4;
  }
  float* out = summ + (size_t)bkj * 32 * DIN;
  #pragma unroll
  for (int n = 0; n < 16; n++){
    out[n*DIN + d] = ap[n];
    out[(16 + n)*DIN + d] = h[n];
  }
}

// ---------------- K5: combine chunk summaries (batched prefetch) ----------------
__global__ __launch_bounds__(192) void k5_comb(const float* __restrict__ summ, float* __restrict__ hinit){
  int bkn = blockIdx.x;          // (b*4+k)*16 + n
  int n = bkn & 15, bk = bkn >> 4;
  int d = threadIdx.x;
  float hc = 0.f;
  for (int jb = 0; jb < JCH; jb += 8){
    float av[8], hv[8];
    #pragma unroll
    for (int i = 0; i < 8; i++){
      size_t sb = ((size_t)(bk*JCH + jb + i))*32*DIN;
      av[i] = summ[sb + n*DIN + d];
      hv[i] = summ[sb + (16+n)*DIN + d];
    }
    #pragma unroll
    for (int i = 0; i < 8; i++){
      hinit[((size_t)(bk*JCH + jb + i))*16*DIN + n*DIN + d] = hc;
      hc = fmaf(av[i], hc, hv[i]);
    }
  }
}

// ---------------- K6: scan pass 2 (emit ys) ----------------
__global__ __launch_bounds__(192) void k6_scan2(const float* __restrict__ xdbl, const float* __restrict__ xx,
    const float* __restrict__ dtw, const float* __restrict__ dtb, const float* __restrict__ alogs,
    const float* __restrict__ Ds, const float* __restrict__ hinit, float* __restrict__ ys){
  int bkj = blockIdx.x;
  int j = bkj & (JCH-1), k = (bkj >> 7) & 3, b = bkj >> 9;
  int d = threadIdx.x;
  float wv[6];
  #pragma unroll
  for (int r = 0; r < 6; r++) wv[r] = dtw[(k*DIN + d)*6 + r];
  float bb = dtb[k*DIN + d];
  float A2[16];
  #pragma unroll
  for (int n = 0; n < 16; n++) A2[n] = -__expf(alogs[(k*DIN + d)*16 + n]) * 1.44269504088896f;
  float Dv = Ds[k*DIN + d];
  float h[16];
  const float* hi = hinit + (size_t)bkj*16*DIN;
  #pragma unroll
  for (int n = 0; n < 16; n++) h[n] = hi[n*DIN + d];
  const float4* r4 = (const float4*)(xdbl + (((size_t)(b*4 + k))*4096 + j*QLEN)*REC);
  const float* xb = xx + (size_t)b*4096*DIN;
  float* yb = ys + (((size_t)(b*4 + k))*4096 + j*QLEN)*DIN + d;
  for (int t0 = 0; t0 < QLEN; t0++){
    int t = j*QLEN + t0;
    float4 q[10];
    #pragma unroll
    for (int i = 0; i < 10; i++) q[i] = r4[i];
    const float* rr = (const float*)q;
    float u = xb[(size_t)src_of(k, t)*DIN + d];
    float draw = bb;
    #pragma unroll
    for (int r = 0; r < 6; r++) draw = fmaf(wv[r], rr[r], draw);
    float delta = softplusf_(draw);
    float du = delta * u;
    float y = 0.f;
    #pragma unroll
    for (int n = 0; n < 16; n++){
      float a = exp2f(A2[n] * delta);
      h[n] = fmaf(a, h[n], du * rr[6 + n]);
      y = fmaf(h[n], rr[22 + n], y);
    }
    y = fmaf(Dv, u, y);
    yb[(size_t)t0*DIN] = y;
    r4 += REC/4;
  }
}

// ---------------- K7: merge directions + out_norm + gate ----------------
__global__ __launch_bounds__(192) void k7_comb(const float* __restrict__ ys, const float* __restrict__ z,
    const float* __restrict__ onw, const float* __restrict__ onb, float* __restrict__ gated){
  int row = blockIdx.x;          // b*4096 + l
  int b = row >> 12, l = row & 4095;
  int d = threadIdx.x;
  int hh = l >> 6, ww = l & 63;
  int lt = (ww << 6) | hh;
  size_t base = (size_t)b * 4 * 4096 * DIN;
  float y = ys[base + ((size_t)0*4096 + l)*DIN + d]
          + ys[base + ((size_t)1*4096 + lt)*DIN + d]
          + ys[base + ((size_t)2*4096 + (4095 - l))*DIN + d]
          + ys[base + ((size_t)3*4096 + (4095 - lt))*DIN + d];
  __shared__ float red[6];
  float s = y, ss = y*y;
  #pragma unroll
  for (int off = 32; off > 0; off >>= 1){ s += __shfl_down(s, off); ss += __shfl_down(ss, off); }
  int wid = d >> 6;
  if ((d & 63) == 0){ red[wid] = s; red[3 + wid] = ss; }
  __syncthreads();
  float S = red[0] + red[1] + red[2], SS = red[3] + red[4] + red[5];
  float mu = S * (1.f/192.f);
  float var = SS * (1.f/192.f) - mu*mu;
  float iv = rsqrtf(var + 1e-5f);
  float yn = (y - mu)*iv*onw[d] + onb[d];
  float zv = z[(size_t)row*DIN + d];
  gated[(size_t)row*DIN + d] = yn * zv * sigmoidf_(zv);
}

// ---------------- K8: out_proj + skip1 residual ----------------
__global__ __launch_bounds__(256) void k8_outproj(const float* __restrict__ gated, const float* __restrict__ WT,
    const float* __restrict__ inp, const float* __restrict__ skip1, float* __restrict__ x1){
  __shared__ float lA[64*98], lB[96*64];
  int tid = threadIdx.x;
  int row0 = blockIdx.x*64, c0 = blockIdx.y*64;
  float acc[4][4] = {};
  int ty = tid >> 4, tx = tid & 15;
  for (int k0 = 0; k0 < 192; k0 += 96){
    __syncthreads();
    stageA_raw_(gated, 192, row0, k0, lA, tid);
    stageB_(WT, 96, 192, k0, c0, lB, tid);
    __syncthreads();
    core96_(lA, lB, ty*4, tx*4, acc);
  }
  #pragma unroll
  for (int i = 0; i < 4; i++){
    int r = row0 + ty*4 + i;
    #pragma unroll
    for (int jj = 0; jj < 4; jj++){
      int c = c0 + tx*4 + jj;
      if (c < 96) x1[(size_t)r*96 + c] = inp[(size_t)r*96 + c]*skip1[c] + acc[i][jj];
    }
  }
}

// ---------------- K9: LN2 + ffn1 (1x1) + bias ----------------
__global__ __launch_bounds__(256) void k9_ffn1(const float* __restrict__ x1,
    const float* __restrict__ lnw, const float* __restrict__ lnb,
    const float* __restrict__ WT, const float* __restrict__ b1, float* __restrict__ t1){
  __shared__ float lA[64*98], lB[96*64], lmu[64], liv[64];
  int tid = threadIdx.x;
  int row0 = blockIdx.x * 64, c0 = blockIdx.y * 64;
  stageA_ln_(x1, row0, lnw, lnb, lA, lmu, liv, tid);
  stageB_(WT, 192, 96, 0, c0, lB, tid);
  __syncthreads();
  float acc[4][4] = {};
  int ty = tid >> 4, tx = tid & 15;
  core96_(lA, lB, ty*4, tx*4, acc);
  #pragma unroll
  for (int i = 0; i < 4; i++){
    int r = row0 + ty*4 + i;
    #pragma unroll
    for (int jj = 0; jj < 4; jj++){
      int c = c0 + tx*4 + jj;
      t1[(size_t)r*192 + c] = acc[i][jj] + b1[c];
    }
  }
}

// ---------------- K10: depthwise 3x3 + GLU (exact gelu) ----------------
__global__ __launch_bounds__(256) void k10_dwglu(const float* __restrict__ t1, const float* __restrict__ cw2,
    const float* __restrict__ cb2, float* __restrict__ g){
  int tid = blockIdx.x*256 + threadIdx.x;
  if (tid >= BN*LL*CC) return;
  int c = tid % 96; int bl = tid / 96;
  int l = bl & 4095, b = bl >> 12;
  int h = l >> 6, w = l & 63;
  float s1 = cb2[c], s2 = cb2[c + 96];
  #pragma unroll
  for (int dh = -1; dh <= 1; dh++){
    int h2 = h + dh; if (h2 < 0 || h2 > 63) continue;
    #pragma unroll
    for (int dw = -1; dw <= 1; dw++){
      int w2 = w + dw; if (w2 < 0 || w2 > 63) continue;
      const float* p = &t1[((size_t)((b<<12) | (h2<<6) | w2))*DIN];
      int tap = (dh+1)*3 + (dw+1);
      s1 = fmaf(p[c],      cw2[c*9 + tap],        s1);
      s2 = fmaf(p[c + 96], cw2[(c + 96)*9 + tap], s2);
    }
  }
  float ge = 0.5f * s1 * (1.f + erff(s1 * 0.7071067811865475f));
  g[tid] = ge * s2;
}

// ---------------- K11: ffn3 (1x1) + skip2 residual ----------------
__global__ __launch_bounds__(256) void k11_ffn3(const float* __restrict__ g, const float* __restrict__ WT,
    const float* __restrict__ x1, const float* __restrict__ skip2, const float* __restrict__ b3,
    float* __restrict__ out){
  __shared__ float lA[64*98], lB[96*64];
  int tid = threadIdx.x;
  int row0 = blockIdx.x*64, c0 = blockIdx.y*64;
  stageA_raw_(g, 96, row0, 0, lA, tid);
  stageB_(WT, 96, 96, 0, c0, lB, tid);
  __syncthreads();
  float acc[4][4] = {};
  int ty = tid >> 4, tx = tid & 15;
  core96_(lA, lB, ty*4, tx*4, acc);
  #pragma unroll
  for (int i = 0; i < 4; i++){
    int r = row0 + ty*4 + i;
    #pragma unroll
    for (int jj = 0; jj < 4; jj++){
      int c = c0 + tx*4 + jj;
      if (c < 96) out[(size_t)r*96 + c] = x1[(size_t)r*96 + c]*skip2[c] + acc[i][jj] + b3[c];
    }
  }
}

// ---------------- launch ----------------
extern "C" void kernel_launch(void* const* d_in, const int* in_sizes, int n_in,
                              void* d_out, int out_size, void* d_ws, size_t ws_size,
                              hipStream_t stream){
  const float* input = (const float*)d_in[0];
  const float* ln1w  = (const float*)d_in[3];
  const float* ln1b  = (const float*)d_in[4];
  const float* skip1 = (const float*)d_in[5];
  const float* skip2 = (const float*)d_in[6];
  const float* ln2w  = (const float*)d_in[7];
  const float* ln2b  = (const float*)d_in[8];
  const float* ipw   = (const float*)d_in[9];
  const float* convw = (const float*)d_in[10];
  const float* convb = (const float*)d_in[11];
  const float* xpw   = (const float*)d_in[12];
  const float* dtw   = (const float*)d_in[13];
  const float* dtb   = (const float*)d_in[14];
  const float* alogs = (const float*)d_in[15];
  const float* Ds    = (const float*)d_in[16];
  const float* onw   = (const float*)d_in[17];
  const float* onb   = (const float*)d_in[18];
  const float* opw   = (const float*)d_in[19];
  const float* f1w   = (const float*)d_in[20];
  const float* f1b   = (const float*)d_in[21];
  const float* f2w   = (const float*)d_in[22];
  const float* f2b   = (const float*)d_in[23];
  const float* f3w   = (const float*)d_in[24];
  const float* f3b   = (const float*)d_in[25];
  float* out = (float*)d_out;
  float* ws  = (float*)d_ws;

  // ws offsets (in floats)
  const size_t O_WT1   = 0;            // 36864
  const size_t O_WT3   = 36864;        // 29184
  const size_t O_WT8   = 66048;        // 18432
  const size_t O_WT9   = 84480;        // 18432
  const size_t O_WT11  = 102912;       // 9216 (end 112128)
  const size_t O_XCONV = 112640;       // 3145728
  const size_t O_Z     = 3258368;      // 3145728
  const size_t O_XX    = 6404096;      // 3145728
  const size_t O_XDBL  = 9549824;      // 2621440 (4*4*4096*40)
  const size_t O_SUMM  = 12171264;     // 12582912 (2048*32*192)
  const size_t O_HINIT = 24754176;     // 6291456 (2048*16*192) -> end 31045632 floats = 124.2 MB
  const size_t O_YS    = O_SUMM;       // alias (summ dead after k5)
  const size_t O_GATED = O_XCONV;      // reuse (xconv dead after k2)
  const size_t O_X1    = O_XX;         // reuse (xx dead after k6)
  const size_t O_T1    = O_Z;          // reuse (z dead after k7)
  const size_t O_G     = O_XDBL;       // reuse (xdbl dead after k6)

  float* WT1  = ws + O_WT1;  float* WT3  = ws + O_WT3;  float* WT8 = ws + O_WT8;
  float* WT9  = ws + O_WT9;  float* WT11 = ws + O_WT11;
  float* xconv = ws + O_XCONV; float* z = ws + O_Z; float* xx = ws + O_XX;
  float* xdbl = ws + O_XDBL; float* summ = ws + O_SUMM; float* hinit = ws + O_HINIT;
  float* ys = ws + O_YS; float* gated = ws + O_GATED; float* x1 = ws + O_X1;
  float* t1 = ws + O_T1; float* g = ws + O_G;

  k0_tr<<<144, 256, 0, stream>>>(ipw, xpw, opw, f1w, f3w, WT1, WT3, WT8, WT9, WT11);
  k1_ln_inproj<<<dim3(256, 6), 256, 0, stream>>>(input, ln1w, ln1b, WT1, xconv, z);
  k2_conv<<<(BN*LL*DIN + 255)/256, 256, 0, stream>>>(xconv, convw, convb, xx);
  k3_xdbl<<<dim3(256, 3), 256, 0, stream>>>(xx, WT3, xdbl);
  k4_scan1<<<BN*KD*JCH, 192, 0, stream>>>(xdbl, xx, dtw, dtb, alogs, summ);
  k5_comb<<<BN*KD*NS, 192, 0, stream>>>(summ, hinit);
  k6_scan2<<<BN*KD*JCH, 192, 0, stream>>>(xdbl, xx, dtw, dtb, alogs, Ds, hinit, ys);
  k7_comb<<<BN*LL, 192, 0, stream>>>(ys, z, onw, onb, gated);
  k8_outproj<<<dim3(256, 2), 256, 0, stream>>>(gated, WT8, input, skip1, x1);
  k9_ffn1<<<dim3(256, 3), 256, 0, stream>>>(x1, ln2w, ln2b, WT9, f1b, t1);
  k10_dwglu<<<(BN*LL*CC + 255)/256, 256, 0, stream>>>(t1, f2w, f2b, g);
  k11_ffn3<<<dim3(256, 2), 256, 0, stream>>>(g, WT11, x1, skip2, f3b, out);
  (void)in_sizes; (void)n_in; (void)out_size; (void)ws_size;
}

// Round 3
// 410.876 us; speedup vs baseline: 1.1531x; 1.0965x over previous
//
#include <hip/hip_runtime.h>
#include <math.h>

#define BN  4
#define LL  4096
#define CC  96
#define DIN 192
#define KD  4
#define NS  16
#define RK  6
#define QLEN 32
#define JCH  128   // LL/QLEN
#define REC  40    // padded record stride (floats), 160B aligned

__device__ __forceinline__ float sigmoidf_(float x){ return 1.f/(1.f+__expf(-x)); }
__device__ __forceinline__ float softplusf_(float x){
  return x > 20.f ? x : 0.69314718056f * __log2f(1.f + exp2f(x * 1.44269504089f));
}

// ---------------- GEMM building blocks ----------------
// LDS A: [64 rows][96 +2 pad], LDS B: [96 k][64 cols]

__device__ __forceinline__ void stageB_(const float* __restrict__ WT, int NTOT, int KTOT, int k0, int c0,
                                        float* __restrict__ lB, int tid){
  for (int idx = tid; idx < 96*64; idx += 256){
    int k = idx >> 6, c = idx & 63;
    int gk = k0 + k, gc = c0 + c;
    lB[idx] = (gc < NTOT && gk < KTOT) ? WT[(size_t)gk*NTOT + gc] : 0.f;
  }
}

__device__ __forceinline__ void stageA_raw_(const float* __restrict__ A, int SR, int row0, int k0,
                                            float* __restrict__ lA, int tid){
  for (int idx = tid; idx < 64*96; idx += 256){
    int r = idx / 96, k = idx - r*96;
    lA[r*98 + k] = A[(size_t)(row0 + r)*SR + k0 + k];
  }
}

__device__ __forceinline__ void stageA_ln_(const float* __restrict__ A, int row0,
                                           const float* __restrict__ w, const float* __restrict__ bv,
                                           float* __restrict__ lA, float* __restrict__ lmu,
                                           float* __restrict__ liv, int tid){
  for (int idx = tid; idx < 64*96; idx += 256){
    int r = idx / 96, k = idx - r*96;
    lA[r*98 + k] = A[(size_t)(row0 + r)*96 + k];
  }
  __syncthreads();
  {
    int r = tid >> 2, p = tid & 3;
    float s = 0.f, ss = 0.f;
    #pragma unroll
    for (int i = 0; i < 24; i++){ float v = lA[r*98 + p*24 + i]; s += v; ss += v*v; }
    s  += __shfl_xor(s, 1);  ss += __shfl_xor(ss, 1);
    s  += __shfl_xor(s, 2);  ss += __shfl_xor(ss, 2);
    if (p == 0){
      float mu = s*(1.f/96.f);
      float var = ss*(1.f/96.f) - mu*mu;
      lmu[r] = mu; liv[r] = rsqrtf(var + 1e-5f);
    }
  }
  __syncthreads();
  for (int idx = tid; idx < 64*96; idx += 256){
    int r = idx / 96, k = idx - r*96;
    float v = lA[r*98 + k];
    lA[r*98 + k] = (v - lmu[r])*liv[r]*w[k] + bv[k];
  }
}

__device__ __forceinline__ void core96_(const float* __restrict__ lA, const float* __restrict__ lB,
                                        int r0, int c0, float acc[4][4]){
  #pragma unroll 4
  for (int k = 0; k < 96; k += 2){
    float2 a[4];
    #pragma unroll
    for (int i = 0; i < 4; i++) a[i] = *(const float2*)&lA[(r0+i)*98 + k];
    float4 b0 = *(const float4*)&lB[k*64 + c0];
    float4 b1 = *(const float4*)&lB[(k+1)*64 + c0];
    #pragma unroll
    for (int i = 0; i < 4; i++){
      acc[i][0] = fmaf(a[i].x, b0.x, acc[i][0]); acc[i][0] = fmaf(a[i].y, b1.x, acc[i][0]);
      acc[i][1] = fmaf(a[i].x, b0.y, acc[i][1]); acc[i][1] = fmaf(a[i].y, b1.y, acc[i][1]);
      acc[i][2] = fmaf(a[i].x, b0.z, acc[i][2]); acc[i][2] = fmaf(a[i].y, b1.z, acc[i][2]);
      acc[i][3] = fmaf(a[i].x, b0.w, acc[i][3]); acc[i][3] = fmaf(a[i].y, b1.w, acc[i][3]);
    }
  }
}

// ---------------- K0: weight transposes ----------------
__global__ __launch_bounds__(256) void k0_tr(const float* __restrict__ ipw, const float* __restrict__ xpw,
    const float* __restrict__ opw, const float* __restrict__ f1w, const float* __restrict__ f3w,
    float* __restrict__ WT1, float* __restrict__ WT3, float* __restrict__ WT8,
    float* __restrict__ WT9, float* __restrict__ WT11){
  int tid = blockIdx.x*256 + threadIdx.x;
  if (tid < 96*384){ int k = tid/384, j = tid%384; WT1[tid]  = ipw[j*96 + k]; }
  if (tid < 192*152){ int d = tid/152, kc = tid%152; WT3[tid] = xpw[kc*192 + d]; }
  if (tid < 192*96){ int d = tid/96, c = tid%96; WT8[tid]  = opw[c*192 + d]; }
  if (tid < 96*192){ int k = tid/192, j = tid%192; WT9[tid]  = f1w[j*96 + k]; }
  if (tid < 96*96){  int k = tid/96,  j = tid%96;  WT11[tid] = f3w[j*96 + k]; }
}

// ---------------- K1: LN1 + in_proj ----------------
__global__ __launch_bounds__(256) void k1_ln_inproj(const float* __restrict__ x,
    const float* __restrict__ lnw, const float* __restrict__ lnb,
    const float* __restrict__ WT, float* __restrict__ xconv, float* __restrict__ z){
  __shared__ float lA[64*98], lB[96*64], lmu[64], liv[64];
  int tid = threadIdx.x;
  int row0 = blockIdx.x * 64, c0 = blockIdx.y * 64;
  stageA_ln_(x, row0, lnw, lnb, lA, lmu, liv, tid);
  stageB_(WT, 384, 96, 0, c0, lB, tid);
  __syncthreads();
  float acc[4][4] = {};
  int ty = tid >> 4, tx = tid & 15;
  core96_(lA, lB, ty*4, tx*4, acc);
  #pragma unroll
  for (int i = 0; i < 4; i++){
    int r = row0 + ty*4 + i;
    #pragma unroll
    for (int jj = 0; jj < 4; jj++){
      int c = c0 + tx*4 + jj;
      if (c < 192) xconv[(size_t)r*192 + c] = acc[i][jj];
      else         z[(size_t)r*192 + (c - 192)] = acc[i][jj];
    }
  }
}

// ---------------- K2: depthwise 3x3 conv + SiLU ----------------
__global__ __launch_bounds__(256) void k2_conv(const float* __restrict__ xc,
    const float* __restrict__ cw, const float* __restrict__ cb, float* __restrict__ xx){
  int tid = blockIdx.x*256 + threadIdx.x;
  if (tid >= BN*LL*DIN) return;
  int d = tid % DIN; int bl = tid / DIN;
  int l = bl & 4095; int b = bl >> 12;
  int h = l >> 6, w = l & 63;
  float s = cb[d];
  #pragma unroll
  for (int dh = -1; dh <= 1; dh++){
    int h2 = h + dh; if (h2 < 0 || h2 > 63) continue;
    #pragma unroll
    for (int dw = -1; dw <= 1; dw++){
      int w2 = w + dw; if (w2 < 0 || w2 > 63) continue;
      s = fmaf(xc[((size_t)((b<<12) | (h2<<6) | w2))*DIN + d], cw[d*9 + (dh+1)*3 + (dw+1)], s);
    }
  }
  xx[tid] = s * sigmoidf_(s);
}

// ---------------- K3: x_proj for 4 directions (scatter, padded records) ----------------
__global__ __launch_bounds__(256) void k3_xdbl(const float* __restrict__ xx,
    const float* __restrict__ WT, float* __restrict__ xdbl){
  __shared__ float lA[64*98], lB[96*64];
  int tid = threadIdx.x;
  int row0 = blockIdx.x * 64, c0 = blockIdx.y * 64;
  float acc[4][4] = {};
  int ty = tid >> 4, tx = tid & 15;
  for (int k0 = 0; k0 < 192; k0 += 96){
    __syncthreads();
    stageA_raw_(xx, 192, row0, k0, lA, tid);
    stageB_(WT, 152, 192, k0, c0, lB, tid);
    __syncthreads();
    core96_(lA, lB, ty*4, tx*4, acc);
  }
  #pragma unroll
  for (int i = 0; i < 4; i++){
    int r = row0 + ty*4 + i;
    int b = r >> 12, l = r & 4095;
    int hh = l >> 6, ww = l & 63;
    int lt = (ww << 6) | hh;
    #pragma unroll
    for (int jj = 0; jj < 4; jj++){
      int kc = c0 + tx*4 + jj;
      if (kc < 152){
        int k = kc / 38, cc = kc - k*38;
        int pos = (k == 0) ? l : (k == 1) ? lt : (k == 2) ? (4095 - l) : (4095 - lt);
        xdbl[(((size_t)(b*4 + k))*4096 + pos)*REC + cc] = acc[i][jj];
      }
    }
  }
}

// ---------------- scan helpers ----------------
__device__ __forceinline__ int src_of(int k, int t){
  if (k == 0) return t;
  if (k == 1) return ((t & 63) << 6) | (t >> 6);
  if (k == 2) return 4095 - t;
  int tt = 4095 - t; return ((tt & 63) << 6) | (tt >> 6);
}

// ---------------- K4: scan pass 1 (chunk summaries, LDS-staged) ----------------
__global__ __launch_bounds__(192) void k4_scan1(const float* __restrict__ xdbl, const float* __restrict__ xx,
    const float* __restrict__ dtw, const float* __restrict__ dtb, const float* __restrict__ alogs,
    float* __restrict__ summ){
  __shared__ float recs[QLEN*REC];   // 5 KB
  __shared__ float us[QLEN*DIN];     // 24 KB
  int bkj = blockIdx.x;
  int j = bkj & (JCH-1), k = (bkj >> 7) & 3, b = bkj >> 9;
  int d = threadIdx.x;
  // stage records (coalesced float4)
  {
    const float4* rsrc = (const float4*)(xdbl + (((size_t)(b*4 + k))*4096 + j*QLEN)*REC);
    float4* rdst = (float4*)recs;
    for (int i = d; i < QLEN*REC/4; i += 192) rdst[i] = rsrc[i];
  }
  // stage u rows (each row coalesced)
  {
    const float* xb = xx + (size_t)b*4096*DIN;
    #pragma unroll 4
    for (int t0 = 0; t0 < QLEN; t0++){
      int row = src_of(k, j*QLEN + t0);
      us[t0*DIN + d] = xb[(size_t)row*DIN + d];
    }
  }
  float wv[6];
  #pragma unroll
  for (int r = 0; r < 6; r++) wv[r] = dtw[(k*DIN + d)*6 + r];
  float bb = dtb[k*DIN + d];
  float A2[16];
  #pragma unroll
  for (int n = 0; n < 16; n++) A2[n] = -__expf(alogs[(k*DIN + d)*16 + n]) * 1.44269504088896f;
  float h[16];
  #pragma unroll
  for (int n = 0; n < 16; n++) h[n] = 0.f;
  float dsum = 0.f;
  __syncthreads();
  for (int t0 = 0; t0 < QLEN; t0++){
    const float* rr = &recs[t0*REC];
    float draw = bb;
    #pragma unroll
    for (int r = 0; r < 6; r++) draw = fmaf(wv[r], rr[r], draw);
    float delta = softplusf_(draw);
    float u = us[t0*DIN + d];
    float du = delta * u;
    dsum += delta;
    #pragma unroll
    for (int n = 0; n < 16; n++){
      float a = exp2f(A2[n] * delta);
      h[n] = fmaf(a, h[n], du * rr[6 + n]);
    }
  }
  float* out = summ + (size_t)bkj * 32 * DIN;
  #pragma unroll
  for (int n = 0; n < 16; n++){
    out[n*DIN + d] = exp2f(A2[n] * dsum);   // product of all decays
    out[(16 + n)*DIN + d] = h[n];
  }
}

// ---------------- K5: combine chunk summaries (batched prefetch) ----------------
__global__ __launch_bounds__(192) void k5_comb(const float* __restrict__ summ, float* __restrict__ hinit){
  int bkn = blockIdx.x;          // (b*4+k)*16 + n
  int n = bkn & 15, bk = bkn >> 4;
  int d = threadIdx.x;
  float hc = 0.f;
  for (int jb = 0; jb < JCH; jb += 8){
    float av[8], hv[8];
    #pragma unroll
    for (int i = 0; i < 8; i++){
      size_t sb = ((size_t)(bk*JCH + jb + i))*32*DIN;
      av[i] = summ[sb + n*DIN + d];
      hv[i] = summ[sb + (16+n)*DIN + d];
    }
    #pragma unroll
    for (int i = 0; i < 8; i++){
      hinit[((size_t)(bk*JCH + jb + i))*16*DIN + n*DIN + d] = hc;
      hc = fmaf(av[i], hc, hv[i]);
    }
  }
}

// ---------------- K6: scan pass 2 (LDS-staged, atomic y accumulate) ----------------
__global__ __launch_bounds__(192) void k6_scan2(const float* __restrict__ xdbl, const float* __restrict__ xx,
    const float* __restrict__ dtw, const float* __restrict__ dtb, const float* __restrict__ alogs,
    const float* __restrict__ Ds, const float* __restrict__ hinit, float* __restrict__ yacc){
  __shared__ float recs[QLEN*REC];
  __shared__ float us[QLEN*DIN];
  int bkj = blockIdx.x;
  int j = bkj & (JCH-1), k = (bkj >> 7) & 3, b = bkj >> 9;
  int d = threadIdx.x;
  {
    const float4* rsrc = (const float4*)(xdbl + (((size_t)(b*4 + k))*4096 + j*QLEN)*REC);
    float4* rdst = (float4*)recs;
    for (int i = d; i < QLEN*REC/4; i += 192) rdst[i] = rsrc[i];
  }
  {
    const float* xb = xx + (size_t)b*4096*DIN;
    #pragma unroll 4
    for (int t0 = 0; t0 < QLEN; t0++){
      int row = src_of(k, j*QLEN + t0);
      us[t0*DIN + d] = xb[(size_t)row*DIN + d];
    }
  }
  float wv[6];
  #pragma unroll
  for (int r = 0; r < 6; r++) wv[r] = dtw[(k*DIN + d)*6 + r];
  float bb = dtb[k*DIN + d];
  float A2[16];
  #pragma unroll
  for (int n = 0; n < 16; n++) A2[n] = -__expf(alogs[(k*DIN + d)*16 + n]) * 1.44269504088896f;
  float Dv = Ds[k*DIN + d];
  float h[16];
  const float* hi = hinit + (size_t)bkj*16*DIN;
  #pragma unroll
  for (int n = 0; n < 16; n++) h[n] = hi[n*DIN + d];
  float* yb = yacc + (size_t)b*4096*DIN;
  __syncthreads();
  for (int t0 = 0; t0 < QLEN; t0++){
    const float* rr = &recs[t0*REC];
    float draw = bb;
    #pragma unroll
    for (int r = 0; r < 6; r++) draw = fmaf(wv[r], rr[r], draw);
    float delta = softplusf_(draw);
    float u = us[t0*DIN + d];
    float du = delta * u;
    float y = 0.f;
    #pragma unroll
    for (int n = 0; n < 16; n++){
      float a = exp2f(A2[n] * delta);
      h[n] = fmaf(a, h[n], du * rr[6 + n]);
      y = fmaf(h[n], rr[22 + n], y);
    }
    y = fmaf(Dv, u, y);
    int row = src_of(k, j*QLEN + t0);
    atomicAdd(&yb[(size_t)row*DIN + d], y);
  }
}

// ---------------- K7: out_norm + gate (reads accumulated y) ----------------
__global__ __launch_bounds__(192) void k7_comb(const float* __restrict__ yacc, const float* __restrict__ z,
    const float* __restrict__ onw, const float* __restrict__ onb, float* __restrict__ gated){
  int row = blockIdx.x;          // b*4096 + l
  int d = threadIdx.x;
  float y = yacc[(size_t)row*DIN + d];
  __shared__ float red[6];
  float s = y, ss = y*y;
  #pragma unroll
  for (int off = 32; off > 0; off >>= 1){ s += __shfl_down(s, off); ss += __shfl_down(ss, off); }
  int wid = d >> 6;
  if ((d & 63) == 0){ red[wid] = s; red[3 + wid] = ss; }
  __syncthreads();
  float S = red[0] + red[1] + red[2], SS = red[3] + red[4] + red[5];
  float mu = S * (1.f/192.f);
  float var = SS * (1.f/192.f) - mu*mu;
  float iv = rsqrtf(var + 1e-5f);
  float yn = (y - mu)*iv*onw[d] + onb[d];
  float zv = z[(size_t)row*DIN + d];
  gated[(size_t)row*DIN + d] = yn * zv * sigmoidf_(zv);
}

// ---------------- K8: out_proj + skip1 residual ----------------
__global__ __launch_bounds__(256) void k8_outproj(const float* __restrict__ gated, const float* __restrict__ WT,
    const float* __restrict__ inp, const float* __restrict__ skip1, float* __restrict__ x1){
  __shared__ float lA[64*98], lB[96*64];
  int tid = threadIdx.x;
  int row0 = blockIdx.x*64, c0 = blockIdx.y*64;
  float acc[4][4] = {};
  int ty = tid >> 4, tx = tid & 15;
  for (int k0 = 0; k0 < 192; k0 += 96){
    __syncthreads();
    stageA_raw_(gated, 192, row0, k0, lA, tid);
    stageB_(WT, 96, 192, k0, c0, lB, tid);
    __syncthreads();
    core96_(lA, lB, ty*4, tx*4, acc);
  }
  #pragma unroll
  for (int i = 0; i < 4; i++){
    int r = row0 + ty*4 + i;
    #pragma unroll
    for (int jj = 0; jj < 4; jj++){
      int c = c0 + tx*4 + jj;
      if (c < 96) x1[(size_t)r*96 + c] = inp[(size_t)r*96 + c]*skip1[c] + acc[i][jj];
    }
  }
}

// ---------------- K9: LN2 + ffn1 (1x1) + bias ----------------
__global__ __launch_bounds__(256) void k9_ffn1(const float* __restrict__ x1,
    const float* __restrict__ lnw, const float* __restrict__ lnb,
    const float* __restrict__ WT, const float* __restrict__ b1, float* __restrict__ t1){
  __shared__ float lA[64*98], lB[96*64], lmu[64], liv[64];
  int tid = threadIdx.x;
  int row0 = blockIdx.x * 64, c0 = blockIdx.y * 64;
  stageA_ln_(x1, row0, lnw, lnb, lA, lmu, liv, tid);
  stageB_(WT, 192, 96, 0, c0, lB, tid);
  __syncthreads();
  float acc[4][4] = {};
  int ty = tid >> 4, tx = tid & 15;
  core96_(lA, lB, ty*4, tx*4, acc);
  #pragma unroll
  for (int i = 0; i < 4; i++){
    int r = row0 + ty*4 + i;
    #pragma unroll
    for (int jj = 0; jj < 4; jj++){
      int c = c0 + tx*4 + jj;
      t1[(size_t)r*192 + c] = acc[i][jj] + b1[c];
    }
  }
}

// ---------------- K10: depthwise 3x3 + GLU (exact gelu) ----------------
__global__ __launch_bounds__(256) void k10_dwglu(const float* __restrict__ t1, const float* __restrict__ cw2,
    const float* __restrict__ cb2, float* __restrict__ g){
  int tid = blockIdx.x*256 + threadIdx.x;
  if (tid >= BN*LL*CC) return;
  int c = tid % 96; int bl = tid / 96;
  int l = bl & 4095, b = bl >> 12;
  int h = l >> 6, w = l & 63;
  float s1 = cb2[c], s2 = cb2[c + 96];
  #pragma unroll
  for (int dh = -1; dh <= 1; dh++){
    int h2 = h + dh; if (h2 < 0 || h2 > 63) continue;
    #pragma unroll
    for (int dw = -1; dw <= 1; dw++){
      int w2 = w + dw; if (w2 < 0 || w2 > 63) continue;
      const float* p = &t1[((size_t)((b<<12) | (h2<<6) | w2))*DIN];
      int tap = (dh+1)*3 + (dw+1);
      s1 = fmaf(p[c],      cw2[c*9 + tap],        s1);
      s2 = fmaf(p[c + 96], cw2[(c + 96)*9 + tap], s2);
    }
  }
  float ge = 0.5f * s1 * (1.f + erff(s1 * 0.7071067811865475f));
  g[tid] = ge * s2;
}

// ---------------- K11: ffn3 (1x1) + skip2 residual ----------------
__global__ __launch_bounds__(256) void k11_ffn3(const float* __restrict__ g, const float* __restrict__ WT,
    const float* __restrict__ x1, const float* __restrict__ skip2, const float* __restrict__ b3,
    float* __restrict__ out){
  __shared__ float lA[64*98], lB[96*64];
  int tid = threadIdx.x;
  int row0 = blockIdx.x*64, c0 = blockIdx.y*64;
  stageA_raw_(g, 96, row0, 0, lA, tid);
  stageB_(WT, 96, 96, 0, c0, lB, tid);
  __syncthreads();
  float acc[4][4] = {};
  int ty = tid >> 4, tx = tid & 15;
  core96_(lA, lB, ty*4, tx*4, acc);
  #pragma unroll
  for (int i = 0; i < 4; i++){
    int r = row0 + ty*4 + i;
    #pragma unroll
    for (int jj = 0; jj < 4; jj++){
      int c = c0 + tx*4 + jj;
      if (c < 96) out[(size_t)r*96 + c] = x1[(size_t)r*96 + c]*skip2[c] + acc[i][jj] + b3[c];
    }
  }
}

// ---------------- launch ----------------
extern "C" void kernel_launch(void* const* d_in, const int* in_sizes, int n_in,
                              void* d_out, int out_size, void* d_ws, size_t ws_size,
                              hipStream_t stream){
  const float* input = (const float*)d_in[0];
  const float* ln1w  = (const float*)d_in[3];
  const float* ln1b  = (const float*)d_in[4];
  const float* skip1 = (const float*)d_in[5];
  const float* skip2 = (const float*)d_in[6];
  const float* ln2w  = (const float*)d_in[7];
  const float* ln2b  = (const float*)d_in[8];
  const float* ipw   = (const float*)d_in[9];
  const float* convw = (const float*)d_in[10];
  const float* convb = (const float*)d_in[11];
  const float* xpw   = (const float*)d_in[12];
  const float* dtw   = (const float*)d_in[13];
  const float* dtb   = (const float*)d_in[14];
  const float* alogs = (const float*)d_in[15];
  const float* Ds    = (const float*)d_in[16];
  const float* onw   = (const float*)d_in[17];
  const float* onb   = (const float*)d_in[18];
  const float* opw   = (const float*)d_in[19];
  const float* f1w   = (const float*)d_in[20];
  const float* f1b   = (const float*)d_in[21];
  const float* f2w   = (const float*)d_in[22];
  const float* f2b   = (const float*)d_in[23];
  const float* f3w   = (const float*)d_in[24];
  const float* f3b   = (const float*)d_in[25];
  float* out = (float*)d_out;
  float* ws  = (float*)d_ws;

  // ws offsets (in floats)
  const size_t O_WT1   = 0;            // 36864
  const size_t O_WT3   = 36864;        // 29184
  const size_t O_WT8   = 66048;        // 18432
  const size_t O_WT9   = 84480;        // 18432
  const size_t O_WT11  = 102912;       // 9216 (end 112128)
  const size_t O_XCONV = 112640;       // 3145728
  const size_t O_Z     = 3258368;      // 3145728
  const size_t O_XX    = 6404096;      // 3145728
  const size_t O_XDBL  = 9549824;      // 2621440 (4*4*4096*40)
  const size_t O_SUMM  = 12171264;     // 12582912 (2048*32*192)
  const size_t O_HINIT = 24754176;     // 6291456 (2048*16*192) -> end 31045632 floats = 124.2 MB
  const size_t O_YACC  = O_SUMM;       // alias (summ dead after k5); 3145728 floats
  const size_t O_GATED = O_XCONV;      // reuse (xconv dead after k2)
  const size_t O_X1    = O_XX;         // reuse (xx dead after k6)
  const size_t O_T1    = O_Z;          // reuse (z dead after k7)
  const size_t O_G     = O_XDBL;       // reuse (xdbl dead after k6)

  float* WT1  = ws + O_WT1;  float* WT3  = ws + O_WT3;  float* WT8 = ws + O_WT8;
  float* WT9  = ws + O_WT9;  float* WT11 = ws + O_WT11;
  float* xconv = ws + O_XCONV; float* z = ws + O_Z; float* xx = ws + O_XX;
  float* xdbl = ws + O_XDBL; float* summ = ws + O_SUMM; float* hinit = ws + O_HINIT;
  float* yacc = ws + O_YACC; float* gated = ws + O_GATED; float* x1 = ws + O_X1;
  float* t1 = ws + O_T1; float* g = ws + O_G;

  k0_tr<<<144, 256, 0, stream>>>(ipw, xpw, opw, f1w, f3w, WT1, WT3, WT8, WT9, WT11);
  k1_ln_inproj<<<dim3(256, 6), 256, 0, stream>>>(input, ln1w, ln1b, WT1, xconv, z);
  k2_conv<<<(BN*LL*DIN + 255)/256, 256, 0, stream>>>(xconv, convw, convb, xx);
  k3_xdbl<<<dim3(256, 3), 256, 0, stream>>>(xx, WT3, xdbl);
  k4_scan1<<<BN*KD*JCH, 192, 0, stream>>>(xdbl, xx, dtw, dtb, alogs, summ);
  k5_comb<<<BN*KD*NS, 192, 0, stream>>>(summ, hinit);
  hipMemsetAsync(yacc, 0, (size_t)BN*LL*DIN*sizeof(float), stream);
  k6_scan2<<<BN*KD*JCH, 192, 0, stream>>>(xdbl, xx, dtw, dtb, alogs, Ds, hinit, yacc);
  k7_comb<<<BN*LL, 192, 0, stream>>>(yacc, z, onw, onb, gated);
  k8_outproj<<<dim3(256, 2), 256, 0, stream>>>(gated, WT8, input, skip1, x1);
  k9_ffn1<<<dim3(256, 3), 256, 0, stream>>>(x1, ln2w, ln2b, WT9, f1b, t1);
  k10_dwglu<<<(BN*LL*CC + 255)/256, 256, 0, stream>>>(t1, f2w, f2b, g);
  k11_ffn3<<<dim3(256, 2), 256, 0, stream>>>(g, WT11, x1, skip2, f3b, out);
  (void)in_sizes; (void)n_in; (void)out_size; (void)ws_size;
}